// Round 1
// baseline (750.397 us; speedup 1.0000x reference)
//
#include <hip/hip_runtime.h>

// Problem constants (also derived from in_sizes at launch for safety).
#define PENALTY_N 0.1f

// ---------------------------------------------------------------------------
// Kernel 1: initialize output buffer.
// d_out[0..nN)  = nodes_traffic (the base values the scatter accumulates into)
// d_out[nN]     = 0 (accumulator for total_service_efficiency)
// ---------------------------------------------------------------------------
__global__ void init_out_kernel(const float* __restrict__ traffic,
                                float* __restrict__ out, int nN) {
    int i = blockIdx.x * blockDim.x + threadIdx.x;
    if (i < nN) {
        out[i] = traffic[i];
    } else if (i == nN) {
        out[i] = 0.0f;
    }
}

// ---------------------------------------------------------------------------
// Kernel 2: per-edge scatter.
//   t = |traffic[src] - traffic[dst]| * n * w
//   out[src] -= t ; out[dst] += t
// Reads of `traffic` are from the ORIGINAL array (matches reference), so the
// edge loop is order-independent; only the accumulation needs atomics.
// Vectorized 4 edges / thread-iteration: int4 src, int4 dst, float4 w.
// ---------------------------------------------------------------------------
__global__ __launch_bounds__(256) void edge_scatter_kernel(
    const int* __restrict__ src_idx,
    const int* __restrict__ dst_idx,
    const float* __restrict__ w,
    const float* __restrict__ traffic,
    float* __restrict__ out,
    int nE) {
    const int tid = blockIdx.x * blockDim.x + threadIdx.x;
    const int stride = gridDim.x * blockDim.x;

    const int nvec = nE >> 2;  // nE assumed %4==0 for the vector body
    const int4* __restrict__ src4 = (const int4*)src_idx;
    const int4* __restrict__ dst4 = (const int4*)dst_idx;
    const float4* __restrict__ w4 = (const float4*)w;

    for (int v = tid; v < nvec; v += stride) {
        int4 s = src4[v];
        int4 d = dst4[v];
        float4 ww = w4[v];

        {
            float t = fabsf(traffic[s.x] - traffic[d.x]) * (PENALTY_N * ww.x);
            atomicAdd(&out[s.x], -t);
            atomicAdd(&out[d.x], t);
        }
        {
            float t = fabsf(traffic[s.y] - traffic[d.y]) * (PENALTY_N * ww.y);
            atomicAdd(&out[s.y], -t);
            atomicAdd(&out[d.y], t);
        }
        {
            float t = fabsf(traffic[s.z] - traffic[d.z]) * (PENALTY_N * ww.z);
            atomicAdd(&out[s.z], -t);
            atomicAdd(&out[d.z], t);
        }
        {
            float t = fabsf(traffic[s.w] - traffic[d.w]) * (PENALTY_N * ww.w);
            atomicAdd(&out[s.w], -t);
            atomicAdd(&out[d.w], t);
        }
    }

    // Scalar tail (nE % 4 != 0) — not expected for 6.4M, but correct anyway.
    for (int e = (nvec << 2) + tid; e < nE; e += stride) {
        int s = src_idx[e];
        int d = dst_idx[e];
        float t = fabsf(traffic[s] - traffic[d]) * (PENALTY_N * w[e]);
        atomicAdd(&out[s], -t);
        atomicAdd(&out[d], t);
    }
}

// ---------------------------------------------------------------------------
// Kernel 3: total_service_efficiency = sum(yield * new_traffic - cost)
// new_traffic is d_out[0..nN); result accumulates into d_out[nN].
// ---------------------------------------------------------------------------
__global__ __launch_bounds__(256) void reduce_kernel(
    const float* __restrict__ new_traffic,
    const float* __restrict__ yield_rate,
    const float* __restrict__ cost,
    float* __restrict__ total,  // == d_out + nN
    int nN) {
    const int tid = blockIdx.x * blockDim.x + threadIdx.x;
    const int stride = gridDim.x * blockDim.x;

    float acc = 0.0f;
    for (int i = tid; i < nN; i += stride) {
        acc = fmaf(yield_rate[i], new_traffic[i], acc) - cost[i];
    }

    // wave-64 butterfly
    #pragma unroll
    for (int off = 32; off > 0; off >>= 1) {
        acc += __shfl_down(acc, off, 64);
    }

    __shared__ float wsum[4];  // 256 threads = 4 waves
    const int lane = threadIdx.x & 63;
    const int wid = threadIdx.x >> 6;
    if (lane == 0) wsum[wid] = acc;
    __syncthreads();
    if (threadIdx.x == 0) {
        float s = wsum[0] + wsum[1] + wsum[2] + wsum[3];
        atomicAdd(total, s);
    }
}

// ---------------------------------------------------------------------------
extern "C" void kernel_launch(void* const* d_in, const int* in_sizes, int n_in,
                              void* d_out, int out_size, void* d_ws, size_t ws_size,
                              hipStream_t stream) {
    const int* edge_index = (const int*)d_in[0];     // (2, E) flat
    const float* edge_weight = (const float*)d_in[1];
    const float* nodes_yield = (const float*)d_in[2];
    const float* nodes_traffic = (const float*)d_in[3];
    const float* nodes_cost = (const float*)d_in[4];
    float* out = (float*)d_out;

    const int nE = in_sizes[1];   // 6,400,000
    const int nN = in_sizes[2];   // 100,000

    const int* src_idx = edge_index;
    const int* dst_idx = edge_index + nE;

    // 1. init: out[0..nN) = traffic, out[nN] = 0
    {
        int total = nN + 1;
        int grid = (total + 255) / 256;
        init_out_kernel<<<grid, 256, 0, stream>>>(nodes_traffic, out, nN);
    }

    // 2. edge scatter (grid-stride, vectorized x4)
    {
        int grid = 2048;  // ~8 blocks/CU, grid-stride over 1.6M vec4 groups
        edge_scatter_kernel<<<grid, 256, 0, stream>>>(src_idx, dst_idx, edge_weight,
                                                      nodes_traffic, out, nE);
    }

    // 3. reduction into out[nN]
    {
        int grid = 256;
        reduce_kernel<<<grid, 256, 0, stream>>>(out, nodes_yield, nodes_cost,
                                                out + nN, nN);
    }
}

// Round 2
// 227.039 us; speedup vs baseline: 3.3051x; 3.3051x over previous
//
#include <hip/hip_runtime.h>

#define PENALTY_N 0.1f
#define NPART 4          // node-range partitions
#define CP 25000         // nodes per partition (LDS floats per block = 100 KB)
#define MAX_BPP 64       // max blocks (edge slices) per partition
#define ABLK 1024        // threads per block, partition kernel

// ---------------------------------------------------------------------------
// Kernel A: partitioned scatter with LDS privatization.
// Block = (partition p, edge-slice b).  LDS holds partial sums for nodes
// [p*CP, p*CP+CP).  Scans its slice of ALL edges; endpoints in range get an
// LDS float atomic; everything else is skipped.  Flush = plain stores to
// private scratch (no global atomics at all).
// block 0 / thread 0 also zeroes the scalar accumulator out[nN].
// ---------------------------------------------------------------------------
__global__ __launch_bounds__(ABLK) void part_scatter_kernel(
    const int* __restrict__ src_idx,
    const int* __restrict__ dst_idx,
    const float* __restrict__ w,
    const float* __restrict__ traffic,
    float* __restrict__ scratch,   // [P*Bpp][CP]
    float* __restrict__ out_scalar,
    int nE, int nN, int Bpp) {
    __shared__ float hist[CP];

    const int p = blockIdx.x / Bpp;    // partition
    const int b = blockIdx.x % Bpp;    // edge slice
    const int lo = p * CP;
    const unsigned csz = (unsigned)min(CP, nN - lo);  // valid nodes this part.
    const int tid = threadIdx.x;

    if (blockIdx.x == 0 && tid == 0) *out_scalar = 0.0f;

    for (int i = tid; i < CP; i += ABLK) hist[i] = 0.0f;
    __syncthreads();

    // vectorized edge scan (4 edges / iter)
    const int nvec = nE >> 2;
    const int4* __restrict__ src4 = (const int4*)src_idx;
    const int4* __restrict__ dst4 = (const int4*)dst_idx;
    const float4* __restrict__ w4 = (const float4*)w;
    const int stride = Bpp * ABLK;

    for (int v = b * ABLK + tid; v < nvec; v += stride) {
        int4 s = src4[v];
        int4 d = dst4[v];
        float4 ww = w4[v];

        #pragma unroll
        for (int k = 0; k < 4; ++k) {
            int si = (&s.x)[k];
            int di = (&d.x)[k];
            unsigned so = (unsigned)(si - lo);
            unsigned doo = (unsigned)(di - lo);
            bool inS = so < csz;
            bool inD = doo < csz;
            if (inS || inD) {
                float t = fabsf(traffic[si] - traffic[di]) * (PENALTY_N * (&ww.x)[k]);
                if (inS) atomicAdd(&hist[so], -t);
                if (inD) atomicAdd(&hist[doo], t);
            }
        }
    }
    // scalar tail (nE % 4)
    for (int e = (nvec << 2) + b * ABLK + tid; e < nE; e += stride) {
        int si = src_idx[e];
        int di = dst_idx[e];
        unsigned so = (unsigned)(si - lo);
        unsigned doo = (unsigned)(di - lo);
        bool inS = so < csz;
        bool inD = doo < csz;
        if (inS || inD) {
            float t = fabsf(traffic[si] - traffic[di]) * (PENALTY_N * w[e]);
            if (inS) atomicAdd(&hist[so], -t);
            if (inD) atomicAdd(&hist[doo], t);
        }
    }

    __syncthreads();
    // flush private histogram (plain coalesced stores)
    float* dst = scratch + (size_t)blockIdx.x * CP;
    for (unsigned i = tid; i < csz; i += ABLK) dst[i] = hist[i];
}

// ---------------------------------------------------------------------------
// Kernel B: reduce the Bpp private copies per node, add base traffic, write
// new_traffic, and fuse the service-efficiency reduction.
// ---------------------------------------------------------------------------
__global__ __launch_bounds__(256) void part_reduce_kernel(
    const float* __restrict__ scratch,
    const float* __restrict__ traffic,
    const float* __restrict__ yield_rate,
    const float* __restrict__ cost,
    float* __restrict__ out,        // [nN] new_traffic, out[nN] scalar
    int nN, int Bpp) {
    const int tid = blockIdx.x * blockDim.x + threadIdx.x;
    const int stride = gridDim.x * blockDim.x;

    float acc = 0.0f;
    for (int i = tid; i < nN; i += stride) {
        int p = i / CP;
        int off = i - p * CP;
        const float* base = scratch + (size_t)p * Bpp * CP + off;
        float s = traffic[i];
        for (int b = 0; b < Bpp; ++b) s += base[(size_t)b * CP];
        out[i] = s;
        acc = fmaf(yield_rate[i], s, acc) - cost[i];
    }

    #pragma unroll
    for (int off = 32; off > 0; off >>= 1) acc += __shfl_down(acc, off, 64);

    __shared__ float wsum[4];
    const int lane = threadIdx.x & 63;
    const int wid = threadIdx.x >> 6;
    if (lane == 0) wsum[wid] = acc;
    __syncthreads();
    if (threadIdx.x == 0)
        atomicAdd(&out[nN], wsum[0] + wsum[1] + wsum[2] + wsum[3]);
}

// ---------------------------------------------------------------------------
// Fallback path (ws too small): original direct-atomic version.
// ---------------------------------------------------------------------------
__global__ void init_out_kernel(const float* __restrict__ traffic,
                                float* __restrict__ out, int nN) {
    int i = blockIdx.x * blockDim.x + threadIdx.x;
    if (i < nN) out[i] = traffic[i];
    else if (i == nN) out[i] = 0.0f;
}

__global__ __launch_bounds__(256) void edge_scatter_kernel(
    const int* __restrict__ src_idx, const int* __restrict__ dst_idx,
    const float* __restrict__ w, const float* __restrict__ traffic,
    float* __restrict__ out, int nE) {
    const int tid = blockIdx.x * blockDim.x + threadIdx.x;
    const int stride = gridDim.x * blockDim.x;
    for (int e = tid; e < nE; e += stride) {
        int s = src_idx[e];
        int d = dst_idx[e];
        float t = fabsf(traffic[s] - traffic[d]) * (PENALTY_N * w[e]);
        atomicAdd(&out[s], -t);
        atomicAdd(&out[d], t);
    }
}

__global__ __launch_bounds__(256) void reduce_kernel(
    const float* __restrict__ new_traffic, const float* __restrict__ yield_rate,
    const float* __restrict__ cost, float* __restrict__ total, int nN) {
    const int tid = blockIdx.x * blockDim.x + threadIdx.x;
    const int stride = gridDim.x * blockDim.x;
    float acc = 0.0f;
    for (int i = tid; i < nN; i += stride)
        acc = fmaf(yield_rate[i], new_traffic[i], acc) - cost[i];
    #pragma unroll
    for (int off = 32; off > 0; off >>= 1) acc += __shfl_down(acc, off, 64);
    __shared__ float wsum[4];
    const int lane = threadIdx.x & 63;
    const int wid = threadIdx.x >> 6;
    if (lane == 0) wsum[wid] = acc;
    __syncthreads();
    if (threadIdx.x == 0)
        atomicAdd(total, wsum[0] + wsum[1] + wsum[2] + wsum[3]);
}

// ---------------------------------------------------------------------------
extern "C" void kernel_launch(void* const* d_in, const int* in_sizes, int n_in,
                              void* d_out, int out_size, void* d_ws, size_t ws_size,
                              hipStream_t stream) {
    const int* edge_index = (const int*)d_in[0];     // (2, E) flat
    const float* edge_weight = (const float*)d_in[1];
    const float* nodes_yield = (const float*)d_in[2];
    const float* nodes_traffic = (const float*)d_in[3];
    const float* nodes_cost = (const float*)d_in[4];
    float* out = (float*)d_out;

    const int nE = in_sizes[1];
    const int nN = in_sizes[2];
    const int* src_idx = edge_index;
    const int* dst_idx = edge_index + nE;

    const int P = (nN + CP - 1) / CP;   // 4 for nN=100K
    // Pick Bpp (edge slices per partition) to fit scratch in ws.
    int Bpp = (int)(ws_size / ((size_t)P * CP * sizeof(float)));
    if (Bpp > MAX_BPP) Bpp = MAX_BPP;

    if (Bpp >= 4 && P <= 8) {
        float* scratch = (float*)d_ws;
        part_scatter_kernel<<<P * Bpp, ABLK, 0, stream>>>(
            src_idx, dst_idx, edge_weight, nodes_traffic,
            scratch, out + nN, nE, nN, Bpp);
        part_reduce_kernel<<<256, 256, 0, stream>>>(
            scratch, nodes_traffic, nodes_yield, nodes_cost, out, nN, Bpp);
    } else {
        // fallback: direct global atomics
        int grid = (nN + 1 + 255) / 256;
        init_out_kernel<<<grid, 256, 0, stream>>>(nodes_traffic, out, nN);
        edge_scatter_kernel<<<2048, 256, 0, stream>>>(src_idx, dst_idx,
                                                      edge_weight, nodes_traffic,
                                                      out, nE);
        reduce_kernel<<<256, 256, 0, stream>>>(out, nodes_yield, nodes_cost,
                                               out + nN, nN);
    }
}